// Round 6
// baseline (157.916 us; speedup 1.0000x reference)
//
#include <hip/hip_runtime.h>

// LSTM B=32768, T=50, I=2, H=32.
// R18: 2 independent problems per wave (in-wave ILP).
// R12-R17 model: VALUBusy(~50%, incl trans) + wall imply the SIMD issue
// port is only ~55% occupied -> dependency-latency-bound (per-t chain:
// 4-deep MFMA -> exp burst -> rcp -> algebra -> exp -> rcp -> pack), and
// 2 resident waves can't fill the bubbles (R14's 4-wave fix failed on its
// per-t barrier, not on parallelism). Fix: each wave carries TWO
// independent 16-row problems (32 batch rows), fully unrolled per t ->
// compiler interleaves A's MFMA/exp chain with B's algebra. No barriers.
// 1024 waves = 1 wave/SIMD (ILP now in-wave; up to 512 VGPR available).
// W fragments (Aci/Awh/Awl/Awoh/Awol) are SHARED across both problems;
// only h/c-state and x duplicate -> ~200 VGPR.
// x: LDS planes replaced by direct global float2 loads (broadcast across
// q, L1/L2-resident, 1-deep register prefetch) to fit LDS (out only,
// 25.6KB/block). Stagger dropped (no co-resident waves).
// Carried from R17: transposed GEMM (A=W stationary, B=h register-resident,
// k-perm ku(q*8+2p+e)=q*4+p+16e), MFMA ci-init, row-pair pk activations,
// fma-fused algebra, split-precision W and h (RNE cvt_pk), scales folded
// (-log2e/+2log2e), clamps on zg and c (CL=14), batched rcp.

#define TS 50
#define CL 14.0f
#define WPB 4       // waves per block (independent; no barriers)

typedef short short8 __attribute__((ext_vector_type(8)));
typedef float f32x4 __attribute__((ext_vector_type(4)));
typedef float f32x2 __attribute__((ext_vector_type(2)));

__device__ __forceinline__ float fast_exp2(float x) {
    return __builtin_amdgcn_exp2f(x);
}
__device__ __forceinline__ float fast_rcp(float x) {
    return __builtin_amdgcn_rcpf(x);
}
__device__ __forceinline__ f32x2 pexp(f32x2 z) {           // scalar trans x2
    f32x2 r; r.x = fast_exp2(z.x); r.y = fast_exp2(z.y); return r;
}
__device__ __forceinline__ f32x2 prcp(f32x2 v) {           // scalar trans x2
    f32x2 r; r.x = fast_rcp(v.x); r.y = fast_rcp(v.y); return r;
}
__device__ __forceinline__ f32x2 vmin2(f32x2 v, float s) { // -> v_pk_min_f32
    f32x2 r; r.x = fminf(v.x, s); r.y = fminf(v.y, s); return r;
}
// v ~= hi + lo (bf16 each, trunc). returns (lo<<16)|hi
__device__ __forceinline__ unsigned split_pack(float v) {
    unsigned u   = __float_as_uint(v);
    float    res = v - __uint_as_float(u & 0xffff0000u);
    return __builtin_amdgcn_perm(__float_as_uint(res), u, 0x07060302u);
}
// (a & 0xffff) | (b << 16)
__device__ __forceinline__ unsigned lo_pair(unsigned a, unsigned b) {
    return __builtin_amdgcn_perm(b, a, 0x05040100u);
}
// (a >> 16) | (b & 0xffff0000)
__device__ __forceinline__ unsigned hi_pair(unsigned a, unsigned b) {
    return __builtin_amdgcn_perm(b, a, 0x07060302u);
}
// RNE split: whi = [bf16(a) | bf16(b)], wlo = [bf16(a-hi(a)) | bf16(b-hi(b))]
__device__ __forceinline__ void pack2(float a, float b,
                                      unsigned &whi, unsigned &wlo) {
    unsigned h, l;
    asm("v_cvt_pk_bf16_f32 %0, %1, %2" : "=v"(h) : "v"(a), "v"(b));
    float ra = a - __uint_as_float(h << 16);
    float rb = b - __uint_as_float(h & 0xffff0000u);
    asm("v_cvt_pk_bf16_f32 %0, %1, %2" : "=v"(l) : "v"(ra), "v"(rb));
    whi = h; wlo = l;
}

union U4S8 { uint4 v; short8 s; unsigned u[4]; };

__global__ __launch_bounds__(256, 1)
void lsnn_kernel(const float* __restrict__ x,
                 const float* __restrict__ W_ih,
                 const float* __restrict__ W_hh,
                 const float* __restrict__ b_ih,
                 const float* __restrict__ b_hh,
                 const float* __restrict__ W_out,
                 const float* __restrict__ b_out,
                 const float* __restrict__ h0,
                 const float* __restrict__ c0,
                 float* __restrict__ out)
{
    // LDS: out staging only: 4 waves x 32 rows x 50 t x 4B = 25.6 KB.
    __shared__ __align__(16) float out_lds[WPB][32 * TS];

    const int  tid  = threadIdx.x;
    const int  g_w  = tid >> 6;
    const int  lane = tid & 63;
    const int  u0   = lane & 15;     // batch column within each problem
    const int  q    = lane >> 4;     // k-block / D-row group
    const long wbase = ((long)blockIdx.x * WPB + g_w) * 32;

    float* ow = out_lds[g_w];

    const float L2E = 1.4426950408889634f;
    const float SG  = 2.0f * L2E;

    // ---- stationary A-frags (SHARED by both problems): tile n = ub*4+g;
    //      D-row m -> W_hh row R = g*32 + ub*16 + m.
    //      A word p = units (q*4+p, q*4+p+16). ----
    short8 Awh[8], Awl[8], Aci[8];
    #pragma unroll
    for (int n = 0; n < 8; ++n) {
        const int   g  = n & 3, ub = n >> 2;
        const float s  = (g == 2) ? SG : -L2E;
        const int   R  = g * 32 + ub * 16 + u0;
        const float* wr = W_hh + R * 32;
        U4S8 uh, ul;
        #pragma unroll
        for (int p = 0; p < 4; ++p) {
            unsigned p0 = split_pack(wr[q * 4 + p]      * s);
            unsigned p1 = split_pack(wr[q * 4 + p + 16] * s);
            uh.u[p] = lo_pair(p0, p1);
            ul.u[p] = hi_pair(p0, p1);
        }
        Awh[n] = uh.s;  Awl[n] = ul.s;
        U4S8 ux;
        if (q == 0) {   // ci k-rows 0..7: [wh0,wh0,wh1,wh1,wl0,wl1,bh,bl]
            unsigned s0 = split_pack(W_ih[R * 2 + 0] * s);
            unsigned s1 = split_pack(W_ih[R * 2 + 1] * s);
            unsigned sb = split_pack((b_ih[R] + b_hh[R]) * s);
            ux.u[0] = lo_pair(s0, s0);
            ux.u[1] = lo_pair(s1, s1);
            ux.u[2] = hi_pair(s0, s1);
            ux.u[3] = sb;
        } else {
            ux.u[0] = 0u; ux.u[1] = 0u; ux.u[2] = 0u; ux.u[3] = 0u;
        }
        Aci[n] = ux.s;
    }
    // ---- head A-frags: A[m][k] = W_out[ku(k)], uniform over m ----
    short8 Awoh, Awol;
    {
        U4S8 uh, ul;
        #pragma unroll
        for (int p = 0; p < 4; ++p) {
            unsigned p0 = split_pack(W_out[q * 4 + p]);
            unsigned p1 = split_pack(W_out[q * 4 + p + 16]);
            uh.u[p] = lo_pair(p0, p1);
            ul.u[p] = hi_pair(p0, p1);
        }
        Awoh = uh.s;  Awol = ul.s;
    }
    const float bout = b_out[0];

    // ---- per-problem recurrent state (pb = 0: rows wbase+u0,
    //      pb = 1: rows wbase+16+u0) ----
    U4S8 Bhh[2], Bhl[2];
    f32x2 cst2[2][4];
    float2 xcur[2];
    #pragma unroll
    for (int pb = 0; pb < 2; ++pb) {
        const long row = wbase + pb * 16 + u0;
        const float* hp = h0 + row * 32 + q * 4;
        float4 ha = *(const float4*)hp;
        float4 hb = *(const float4*)(hp + 16);
        pack2(ha.x, hb.x, Bhh[pb].u[0], Bhl[pb].u[0]);
        pack2(ha.y, hb.y, Bhh[pb].u[1], Bhl[pb].u[1]);
        pack2(ha.z, hb.z, Bhh[pb].u[2], Bhl[pb].u[2]);
        pack2(ha.w, hb.w, Bhh[pb].u[3], Bhl[pb].u[3]);
        #pragma unroll
        for (int ub = 0; ub < 2; ++ub)
            #pragma unroll
            for (int rr = 0; rr < 2; ++rr)
                cst2[pb][ub * 2 + rr] =
                    *(const f32x2*)(c0 + row * 32 + ub * 16 + q * 4 + 2 * rr);
        xcur[pb] = *(const float2*)(x + row * 100);   // t=0 prefetch
    }

    const f32x4 ZV = {0.f, 0.f, 0.f, 0.f};

    #pragma unroll 1
    for (int t = 0; t < TS; ++t) {
        #pragma unroll
        for (int pb = 0; pb < 2; ++pb) {
            // ---- Bx from prefetched x (broadcast across q) ----
            unsigned a0 = split_pack(xcur[pb].x);
            unsigned a1 = split_pack(xcur[pb].y);
            U4S8 Bx;
            Bx.u[0] = a0;
            Bx.u[1] = a1;
            Bx.u[2] = lo_pair(a0, a1);
            Bx.u[3] = 0x3f803f80u;          // [1.0, 1.0] bf16
            if (t + 1 < TS)
                xcur[pb] = *(const float2*)
                    (x + (wbase + pb * 16 + u0) * 100 + 2 * (t + 1));

            // ---- output head for h_t (skip t=0): D rows all equal ----
            if (t > 0) {
                f32x4 aw = ZV;
                aw = __builtin_amdgcn_mfma_f32_16x16x32_bf16(Awoh, Bhh[pb].s, aw, 0, 0, 0);
                aw = __builtin_amdgcn_mfma_f32_16x16x32_bf16(Awoh, Bhl[pb].s, aw, 0, 0, 0);
                aw = __builtin_amdgcn_mfma_f32_16x16x32_bf16(Awol, Bhh[pb].s, aw, 0, 0, 0);
                if (q == 0) ow[(pb * 16 + u0) * TS + (t - 1)] = aw[0] + bout;
            }

            // ---- gates: ci-MFMA + 3 split MFMAs per tile ----
            f32x4 acc[8];
            #pragma unroll
            for (int n = 0; n < 8; ++n)
                acc[n] = __builtin_amdgcn_mfma_f32_16x16x32_bf16(Aci[n], Bx.s, ZV, 0, 0, 0);
            #pragma unroll
            for (int n = 0; n < 8; ++n) {
                acc[n] = __builtin_amdgcn_mfma_f32_16x16x32_bf16(Awh[n], Bhh[pb].s, acc[n], 0, 0, 0);
                acc[n] = __builtin_amdgcn_mfma_f32_16x16x32_bf16(Awh[n], Bhl[pb].s, acc[n], 0, 0, 0);
                acc[n] = __builtin_amdgcn_mfma_f32_16x16x32_bf16(Awl[n], Bhh[pb].s, acc[n], 0, 0, 0);
            }

            // ---- activations: 4 row-pair groups gi = ub*2+rr (fma-fused) ----
            f32x2 Bv2[4], Cv2[4], Ev2[4], P12[4], PP2[4];
            #pragma unroll
            for (int ub = 0; ub < 2; ++ub) {
                #pragma unroll
                for (int rr = 0; rr < 2; ++rr) {
                    const int gi = ub * 2 + rr, nb = ub * 4;
                    f32x2 zi = {acc[nb + 0][2*rr], acc[nb + 0][2*rr + 1]};
                    f32x2 zf = {acc[nb + 1][2*rr], acc[nb + 1][2*rr + 1]};
                    f32x2 zg = vmin2((f32x2){acc[nb + 2][2*rr], acc[nb + 2][2*rr + 1]}, CL);
                    f32x2 zo = {acc[nb + 3][2*rr], acc[nb + 3][2*rr + 1]};
                    f32x2 Av = pexp(zi);          // e^{-i}
                    Bv2[gi]  = pexp(zg);          // e^{2g}
                    Ev2[gi]  = pexp(zf);          // e^{-f}
                    Cv2[gi]  = pexp(zo);          // e^{-o}
                    f32x2 Ap = 1.0f + Av;
                    P12[gi] = Ap * Bv2[gi] + Ap;            // (1+Av)(1+Bv)
                    PP2[gi] = P12[gi] * Ev2[gi] + P12[gi];  // *(1+Ev)
                }
            }
            f32x2 R2[4];
            #pragma unroll
            for (int bb = 0; bb < 2; ++bb) {
                f32x2 pr = PP2[2*bb] * PP2[2*bb + 1];
                f32x2 ri = prcp(pr);
                R2[2*bb]     = PP2[2*bb + 1] * ri;
                R2[2*bb + 1] = PP2[2*bb]     * ri;
            }
            f32x2 Dv2[4], Q2[4];
            #pragma unroll
            for (int gi = 0; gi < 4; ++gi) {
                f32x2 fv = P12[gi] * R2[gi];                 // sigmoid(f)
                f32x2 t2 = Ev2[gi] * R2[gi] + R2[gi];        // (1+Ev)*R
                f32x2 ig = Bv2[gi] * t2 - t2;                // (Bv-1)*t2
                f32x2 c  = fv * cst2[pb][gi] + ig;
                cst2[pb][gi] = c;
                f32x2 zc = vmin2(c * SG, CL);
                Dv2[gi] = pexp(zc);                          // e^{2c}
                f32x2 Qp = 1.0f + Cv2[gi];
                Q2[gi]  = Qp * Dv2[gi] + Qp;                 // (1+Cv)(1+Dv)
            }
            f32x2 RQ2[4];
            #pragma unroll
            for (int bb = 0; bb < 2; ++bb) {
                f32x2 qr = Q2[2*bb] * Q2[2*bb + 1];
                f32x2 ri = prcp(qr);
                RQ2[2*bb]     = Q2[2*bb + 1] * ri;
                RQ2[2*bb + 1] = Q2[2*bb]     * ri;
            }
            // ---- h in registers -> B-frag words [h(u), h(u+16)] ----
            float hub[2][4];
            #pragma unroll
            for (int gi = 0; gi < 4; ++gi) {
                f32x2 h2 = Dv2[gi] * RQ2[gi] - RQ2[gi];      // (Dv-1)*RQ
                hub[gi >> 1][2 * (gi & 1)]     = h2.x;
                hub[gi >> 1][2 * (gi & 1) + 1] = h2.y;
            }
            #pragma unroll
            for (int p = 0; p < 4; ++p)
                pack2(hub[0][p], hub[1][p], Bhh[pb].u[p], Bhl[pb].u[p]);
        }
    }

    // ---- final heads for h_50 ----
    #pragma unroll
    for (int pb = 0; pb < 2; ++pb) {
        f32x4 aw = {0.f, 0.f, 0.f, 0.f};
        aw = __builtin_amdgcn_mfma_f32_16x16x32_bf16(Awoh, Bhh[pb].s, aw, 0, 0, 0);
        aw = __builtin_amdgcn_mfma_f32_16x16x32_bf16(Awoh, Bhl[pb].s, aw, 0, 0, 0);
        aw = __builtin_amdgcn_mfma_f32_16x16x32_bf16(Awol, Bhh[pb].s, aw, 0, 0, 0);
        if (q == 0) ow[(pb * 16 + u0) * TS + 49] = aw[0] + bout;
    }

    // ---- coalesced flush of this wave's 1600 contiguous floats ----
    {
        float4* od = (float4*)(out + wbase * 50);
        const float4* os = (const float4*)ow;
        for (int i = lane; i < 400; i += 64) od[i] = os[i];
    }
}

extern "C" void kernel_launch(void* const* d_in, const int* in_sizes, int n_in,
                              void* d_out, int out_size, void* d_ws, size_t ws_size,
                              hipStream_t stream) {
    const float* x     = (const float*)d_in[0];
    const float* W_ih  = (const float*)d_in[1];
    const float* W_hh  = (const float*)d_in[2];
    const float* b_ih  = (const float*)d_in[3];
    const float* b_hh  = (const float*)d_in[4];
    const float* W_out = (const float*)d_in[5];
    const float* b_out = (const float*)d_in[6];
    const float* h0    = (const float*)d_in[7];
    const float* c0    = (const float*)d_in[8];
    float* out = (float*)d_out;

    dim3 grid(32768 / (32 * WPB)), block(64 * WPB);
    lsnn_kernel<<<grid, block, 0, stream>>>(x, W_ih, W_hh, b_ih, b_hh,
                                            W_out, b_out, h0, c0, out);
}

// Round 7
// 151.752 us; speedup vs baseline: 1.0406x; 1.0406x over previous
//
#include <hip/hip_runtime.h>

// LSTM B=32768, T=50, I=2, H=32.
// R19 = R17 champion (90.0us) + 4-way rcp batching + explicit pack pairing.
// Model (fitted R12-R18, six structures): SIMD issue port saturated:
//   wall*clk ~= sum(2*VALU + 16*trans + ~4*MFMA) per wave-t, ~1245 cyc @
//   ~1.4GHz delivered. Parallelism at any granularity (R14 4-wave, R18
//   in-wave dual-problem) is null; only issue-count cuts move wall.
// Trans floor 768 cyc (40 exp + 8 rcp; 5 exp/element irreducible; R16:
// VALU-poly costs 22>16 cyc/pair). This round: rcp 8->4 via 4-way batch
// (prefix/suffix products, 1 prcp per stage instead of 2): -64 +12 cyc;
// overflow-safe for this input (pre-acts ~+-5 -> 4-products <=~1e28; zg/zc
// clamped at CL=14). Plus explicit h2->pack2 pairing (no hub scatter).
// Carried from R17: transposed GEMM (A=W stationary, B=h register-resident,
// k-perm ku(q*8+2p+e)=q*4+p+16e), MFMA ci-init, row-pair pk activations,
// fma-fused algebra, split-precision W and h (RNE cvt_pk), scales folded
// (-log2e/+2log2e), clamps on zg and c (CL=14), anti-phase stagger,
// x pre-split in 3 LDS planes.

#define TS 50
#define XSTR 51     // u32 stride of x plane rows (odd: conflict-free bcast)
#define CL 14.0f
#define WPB 4       // waves per block (independent; no barriers)

typedef short short8 __attribute__((ext_vector_type(8)));
typedef float f32x4 __attribute__((ext_vector_type(4)));
typedef float f32x2 __attribute__((ext_vector_type(2)));

__device__ __forceinline__ float fast_exp2(float x) {
    return __builtin_amdgcn_exp2f(x);
}
__device__ __forceinline__ float fast_rcp(float x) {
    return __builtin_amdgcn_rcpf(x);
}
__device__ __forceinline__ f32x2 pexp(f32x2 z) {           // scalar trans x2
    f32x2 r; r.x = fast_exp2(z.x); r.y = fast_exp2(z.y); return r;
}
__device__ __forceinline__ f32x2 prcp(f32x2 v) {           // scalar trans x2
    f32x2 r; r.x = fast_rcp(v.x); r.y = fast_rcp(v.y); return r;
}
__device__ __forceinline__ f32x2 vmin2(f32x2 v, float s) { // -> v_pk_min_f32
    f32x2 r; r.x = fminf(v.x, s); r.y = fminf(v.y, s); return r;
}
// v ~= hi + lo (bf16 each, trunc). returns (lo<<16)|hi
__device__ __forceinline__ unsigned split_pack(float v) {
    unsigned u   = __float_as_uint(v);
    float    res = v - __uint_as_float(u & 0xffff0000u);
    return __builtin_amdgcn_perm(__float_as_uint(res), u, 0x07060302u);
}
// (a & 0xffff) | (b << 16)
__device__ __forceinline__ unsigned lo_pair(unsigned a, unsigned b) {
    return __builtin_amdgcn_perm(b, a, 0x05040100u);
}
// (a >> 16) | (b & 0xffff0000)
__device__ __forceinline__ unsigned hi_pair(unsigned a, unsigned b) {
    return __builtin_amdgcn_perm(b, a, 0x07060302u);
}
// RNE split: whi = [bf16(a) | bf16(b)], wlo = [bf16(a-hi(a)) | bf16(b-hi(b))]
__device__ __forceinline__ void pack2(float a, float b,
                                      unsigned &whi, unsigned &wlo) {
    unsigned h, l;
    asm("v_cvt_pk_bf16_f32 %0, %1, %2" : "=v"(h) : "v"(a), "v"(b));
    float ra = a - __uint_as_float(h << 16);
    float rb = b - __uint_as_float(h & 0xffff0000u);
    asm("v_cvt_pk_bf16_f32 %0, %1, %2" : "=v"(l) : "v"(ra), "v"(rb));
    whi = h; wlo = l;
}

union U4S8 { uint4 v; short8 s; unsigned u[4]; };

__global__ __launch_bounds__(256, 2)
void lsnn_kernel(const float* __restrict__ x,
                 const float* __restrict__ W_ih,
                 const float* __restrict__ W_hh,
                 const float* __restrict__ b_ih,
                 const float* __restrict__ b_hh,
                 const float* __restrict__ W_out,
                 const float* __restrict__ b_out,
                 const float* __restrict__ h0,
                 const float* __restrict__ c0,
                 float* __restrict__ out)
{
    // LDS: 3 x-planes (3264 B/wave each) + out (3200 B/wave) = 52 KB/block.
    __shared__ __align__(16) unsigned xa0[WPB][16 * XSTR];
    __shared__ __align__(16) unsigned xa1[WPB][16 * XSTR];
    __shared__ __align__(16) unsigned xa2[WPB][16 * XSTR];
    __shared__ __align__(16) float    out_lds[WPB][16 * TS];

    const int  tid  = threadIdx.x;
    const int  g_w  = tid >> 6;
    const int  lane = tid & 63;
    const int  u0   = lane & 15;     // batch column (this lane's batch row)
    const int  q    = lane >> 4;     // k-block / D-row group
    const long b0   = ((long)blockIdx.x * WPB + g_w) * 16;

    unsigned* x0w = xa0[g_w];
    unsigned* x1w = xa1[g_w];
    unsigned* x2w = xa2[g_w];
    float*    ow  = out_lds[g_w];

    // ---- stage x split-packed into 3 planes (per-wave private) ----
    for (int i = lane; i < 800; i += 64) {
        int row = i / 50, t = i - row * 50;          // setup-only divide
        float2 v = *(const float2*)(x + (b0 + row) * 100 + 2 * t);
        unsigned a0 = split_pack(v.x), a1 = split_pack(v.y);
        x0w[row * XSTR + t] = a0;                    // [xh0 | xl0]
        x1w[row * XSTR + t] = a1;                    // [xh1 | xl1]
        x2w[row * XSTR + t] = lo_pair(a0, a1);       // [xh0 | xh1]
    }

    const float L2E = 1.4426950408889634f;
    const float SG  = 2.0f * L2E;

    // ---- stationary A-frags: tile n = ub*4 + gate; D-row m -> W_hh row
    //      R = gate*32 + ub*16 + m.  A word p = units (q*4+p, q*4+p+16). ----
    short8 Awh[8], Awl[8], Aci[8];
    #pragma unroll
    for (int n = 0; n < 8; ++n) {
        const int   g  = n & 3, ub = n >> 2;
        const float s  = (g == 2) ? SG : -L2E;
        const int   R  = g * 32 + ub * 16 + u0;
        const float* wr = W_hh + R * 32;
        U4S8 uh, ul;
        #pragma unroll
        for (int p = 0; p < 4; ++p) {
            unsigned p0 = split_pack(wr[q * 4 + p]      * s);
            unsigned p1 = split_pack(wr[q * 4 + p + 16] * s);
            uh.u[p] = lo_pair(p0, p1);
            ul.u[p] = hi_pair(p0, p1);
        }
        Awh[n] = uh.s;  Awl[n] = ul.s;
        U4S8 ux;
        if (q == 0) {   // ci k-rows 0..7: [wh0,wh0,wh1,wh1,wl0,wl1,bh,bl]
            unsigned s0 = split_pack(W_ih[R * 2 + 0] * s);
            unsigned s1 = split_pack(W_ih[R * 2 + 1] * s);
            unsigned sb = split_pack((b_ih[R] + b_hh[R]) * s);
            ux.u[0] = lo_pair(s0, s0);
            ux.u[1] = lo_pair(s1, s1);
            ux.u[2] = hi_pair(s0, s1);
            ux.u[3] = sb;
        } else {
            ux.u[0] = 0u; ux.u[1] = 0u; ux.u[2] = 0u; ux.u[3] = 0u;
        }
        Aci[n] = ux.s;
    }
    // ---- head A-frags: A[m][k] = W_out[ku(k)], uniform over m ----
    short8 Awoh, Awol;
    {
        U4S8 uh, ul;
        #pragma unroll
        for (int p = 0; p < 4; ++p) {
            unsigned p0 = split_pack(W_out[q * 4 + p]);
            unsigned p1 = split_pack(W_out[q * 4 + p + 16]);
            uh.u[p] = lo_pair(p0, p1);
            ul.u[p] = hi_pair(p0, p1);
        }
        Awoh = uh.s;  Awol = ul.s;
    }
    const float bout = b_out[0];

    // ---- h0 -> B-frags (register-resident recurrent state) ----
    U4S8 Bhh, Bhl;
    {
        const float* hp = h0 + (b0 + u0) * 32 + q * 4;
        float4 ha = *(const float4*)hp;
        float4 hb = *(const float4*)(hp + 16);
        pack2(ha.x, hb.x, Bhh.u[0], Bhl.u[0]);
        pack2(ha.y, hb.y, Bhh.u[1], Bhl.u[1]);
        pack2(ha.z, hb.z, Bhh.u[2], Bhl.u[2]);
        pack2(ha.w, hb.w, Bhh.u[3], Bhl.u[3]);
    }
    // ---- c0: group gi = ub*2+rr -> units ub*16+q*4+(2rr, 2rr+1) ----
    f32x2 cst2[4];
    #pragma unroll
    for (int ub = 0; ub < 2; ++ub)
        #pragma unroll
        for (int rr = 0; rr < 2; ++rr)
            cst2[ub * 2 + rr] =
                *(const f32x2*)(c0 + (b0 + u0) * 32 + ub * 16 + q * 4 + 2 * rr);

    const f32x4 ZV = {0.f, 0.f, 0.f, 0.f};
    const int xbase = u0 * XSTR;

    // ---- x prefetch for t=0 (broadcast across q) ----
    unsigned xw0 = x0w[xbase], xw1 = x1w[xbase], xw2 = x2w[xbase];

    // ---- anti-phase stagger: skew one wave of each co-resident pair ----
    if (((blockIdx.x ^ (blockIdx.x >> 8)) & 1) != 0)
        __builtin_amdgcn_s_sleep(35);    // ~2240 cyc, once

    #pragma unroll 1
    for (int t = 0; t < TS; ++t) {
        U4S8 Bx;
        Bx.u[0] = xw0;  Bx.u[1] = xw1;  Bx.u[2] = xw2;
        Bx.u[3] = 0x3f803f80u;          // [1.0, 1.0] bf16
        if (t + 1 < TS) {
            xw0 = x0w[xbase + t + 1];
            xw1 = x1w[xbase + t + 1];
            xw2 = x2w[xbase + t + 1];
        }

        // ---- output head for h_t (skip t=0): D rows all equal ----
        if (t > 0) {
            f32x4 aw = ZV;
            aw = __builtin_amdgcn_mfma_f32_16x16x32_bf16(Awoh, Bhh.s, aw, 0, 0, 0);
            aw = __builtin_amdgcn_mfma_f32_16x16x32_bf16(Awoh, Bhl.s, aw, 0, 0, 0);
            aw = __builtin_amdgcn_mfma_f32_16x16x32_bf16(Awol, Bhh.s, aw, 0, 0, 0);
            if (q == 0) ow[u0 * TS + (t - 1)] = aw[0] + bout;
        }

        // ---- gates: ci-MFMA + 3 split MFMAs per tile ----
        f32x4 acc[8];
        #pragma unroll
        for (int n = 0; n < 8; ++n)
            acc[n] = __builtin_amdgcn_mfma_f32_16x16x32_bf16(Aci[n], Bx.s, ZV, 0, 0, 0);
        #pragma unroll
        for (int n = 0; n < 8; ++n) {
            acc[n] = __builtin_amdgcn_mfma_f32_16x16x32_bf16(Awh[n], Bhh.s, acc[n], 0, 0, 0);
            acc[n] = __builtin_amdgcn_mfma_f32_16x16x32_bf16(Awh[n], Bhl.s, acc[n], 0, 0, 0);
            acc[n] = __builtin_amdgcn_mfma_f32_16x16x32_bf16(Awl[n], Bhh.s, acc[n], 0, 0, 0);
        }

        // ---- activations: 4 row-pair groups gi = ub*2+rr (fma-fused) ----
        f32x2 Bv2[4], Cv2[4], Ev2[4], P12[4], PP2[4];
        #pragma unroll
        for (int ub = 0; ub < 2; ++ub) {
            #pragma unroll
            for (int rr = 0; rr < 2; ++rr) {
                const int gi = ub * 2 + rr, nb = ub * 4;
                f32x2 zi = {acc[nb + 0][2*rr], acc[nb + 0][2*rr + 1]};
                f32x2 zf = {acc[nb + 1][2*rr], acc[nb + 1][2*rr + 1]};
                f32x2 zg = vmin2((f32x2){acc[nb + 2][2*rr], acc[nb + 2][2*rr + 1]}, CL);
                f32x2 zo = {acc[nb + 3][2*rr], acc[nb + 3][2*rr + 1]};
                f32x2 Av = pexp(zi);          // e^{-i}
                Bv2[gi]  = pexp(zg);          // e^{2g}
                Ev2[gi]  = pexp(zf);          // e^{-f}
                Cv2[gi]  = pexp(zo);          // e^{-o}
                f32x2 Ap = 1.0f + Av;
                P12[gi] = Ap * Bv2[gi] + Ap;            // (1+Av)(1+Bv)
                PP2[gi] = P12[gi] * Ev2[gi] + P12[gi];  // *(1+Ev)
            }
        }
        // ---- 4-way batched reciprocal, stage 1 (2 rcps total) ----
        f32x2 R2[4];
        {
            f32x2 s01 = PP2[0] * PP2[1];
            f32x2 s23 = PP2[2] * PP2[3];
            f32x2 ri  = prcp(s01 * s23);
            f32x2 r01 = s23 * ri;            // 1/(P0*P1)
            f32x2 r23 = s01 * ri;            // 1/(P2*P3)
            R2[0] = PP2[1] * r01;  R2[1] = PP2[0] * r01;
            R2[2] = PP2[3] * r23;  R2[3] = PP2[2] * r23;
        }
        f32x2 Dv2[4], Q2[4];
        #pragma unroll
        for (int gi = 0; gi < 4; ++gi) {
            f32x2 fv = P12[gi] * R2[gi];                 // sigmoid(f)
            f32x2 t2 = Ev2[gi] * R2[gi] + R2[gi];        // (1+Ev)*R
            f32x2 ig = Bv2[gi] * t2 - t2;                // (Bv-1)*t2
            f32x2 c  = fv * cst2[gi] + ig;
            cst2[gi] = c;
            f32x2 zc = vmin2(c * SG, CL);
            Dv2[gi] = pexp(zc);                          // e^{2c}
            f32x2 Qp = 1.0f + Cv2[gi];
            Q2[gi]  = Qp * Dv2[gi] + Qp;                 // (1+Cv)(1+Dv)
        }
        // ---- 4-way batched reciprocal, stage 2 (2 rcps total) ----
        f32x2 RQ2[4];
        {
            f32x2 s01 = Q2[0] * Q2[1];
            f32x2 s23 = Q2[2] * Q2[3];
            f32x2 ri  = prcp(s01 * s23);
            f32x2 r01 = s23 * ri;
            f32x2 r23 = s01 * ri;
            RQ2[0] = Q2[1] * r01;  RQ2[1] = Q2[0] * r01;
            RQ2[2] = Q2[3] * r23;  RQ2[3] = Q2[2] * r23;
        }
        // ---- h -> B-frag words [h(u), h(u+16)]: direct pairing ----
        // word p: (hub0[p], hub1[p]) = (h2[p>>1] comp p&1, h2[2+(p>>1)] comp)
        f32x2 H0 = Dv2[0] * RQ2[0] - RQ2[0];
        f32x2 H1 = Dv2[1] * RQ2[1] - RQ2[1];
        f32x2 H2 = Dv2[2] * RQ2[2] - RQ2[2];
        f32x2 H3 = Dv2[3] * RQ2[3] - RQ2[3];
        pack2(H0.x, H2.x, Bhh.u[0], Bhl.u[0]);
        pack2(H0.y, H2.y, Bhh.u[1], Bhl.u[1]);
        pack2(H1.x, H3.x, Bhh.u[2], Bhl.u[2]);
        pack2(H1.y, H3.y, Bhh.u[3], Bhl.u[3]);
    }

    // ---- final head for h_50 ----
    {
        f32x4 aw = {0.f, 0.f, 0.f, 0.f};
        aw = __builtin_amdgcn_mfma_f32_16x16x32_bf16(Awoh, Bhh.s, aw, 0, 0, 0);
        aw = __builtin_amdgcn_mfma_f32_16x16x32_bf16(Awoh, Bhl.s, aw, 0, 0, 0);
        aw = __builtin_amdgcn_mfma_f32_16x16x32_bf16(Awol, Bhh.s, aw, 0, 0, 0);
        if (q == 0) ow[u0 * TS + 49] = aw[0] + bout;
    }

    // ---- coalesced flush of this wave's 800 contiguous floats ----
    {
        float4* od = (float4*)(out + b0 * 50);
        const float4* os = (const float4*)ow;
        for (int i = lane; i < 200; i += 64) od[i] = os[i];
    }
}

extern "C" void kernel_launch(void* const* d_in, const int* in_sizes, int n_in,
                              void* d_out, int out_size, void* d_ws, size_t ws_size,
                              hipStream_t stream) {
    const float* x     = (const float*)d_in[0];
    const float* W_ih  = (const float*)d_in[1];
    const float* W_hh  = (const float*)d_in[2];
    const float* b_ih  = (const float*)d_in[3];
    const float* b_hh  = (const float*)d_in[4];
    const float* W_out = (const float*)d_in[5];
    const float* b_out = (const float*)d_in[6];
    const float* h0    = (const float*)d_in[7];
    const float* c0    = (const float*)d_in[8];
    float* out = (float*)d_out;

    dim3 grid(32768 / (16 * WPB)), block(64 * WPB);
    lsnn_kernel<<<grid, block, 0, stream>>>(x, W_ih, W_hh, b_ih, b_hh,
                                            W_out, b_out, h0, c0, out);
}

// Round 8
// 148.442 us; speedup vs baseline: 1.0638x; 1.0223x over previous
//
#include <hip/hip_runtime.h>

// LSTM B=32768, T=50, I=2, H=32.
// R20 = R19 (89.5-90.8us) + final counted shaves (floor-validation round).
// Model (fitted R12-R19): SIMD port serializes all pipes; wall tracks
// sum(2*VALU + 16*trans + ~5*MFMA)/wave-t ~= 1245 cyc vs counted min ~1110.
// Trans 704 cyc (40 exp + 4 batched rcp) is irreducible: 5 exp/element
// (LSTM minimum), hw exp beats VALU poly (R16 +47%), rcps already 4-way
// batched (R19). Parallelism null at every granularity (R14/R18).
// This round: (1) v_pk_min_f32 via __builtin_elementwise_min for zg/zc
// clamps (16 scalar fminf -> 8 pk, -16cyc); (2) fused x-plane: one LDS
// plane of ready-made 16B Bx frags {a0,a1,lo01,1.0bf16}, row stride
// 51x16B (2-way bank alias = free), 1 ds_read_b128 replaces 3 ds_read_b32
// + 2 assembly ops (-12cyc). Predict ~87-89us; if >=89, declare floor.
// Carried from R19: transposed GEMM (A=W stationary, B=h register-resident,
// k-perm ku(q*8+2p+e)=q*4+p+16e), MFMA ci-init, row-pair pk activations,
// fma-fused algebra, 4-way batched rcp (prefix/suffix), split-precision
// W and h (RNE cvt_pk), scales folded (-log2e/+2log2e), clamps on zg and
// c only (CL=14), anti-phase stagger, direct pack pairing.

#define TS 50
#define XROW 204    // u32 row stride of fused x plane (816B = 51*16B, odd*16)
#define CL 14.0f
#define WPB 4       // waves per block (independent; no barriers)

typedef short short8 __attribute__((ext_vector_type(8)));
typedef float f32x4 __attribute__((ext_vector_type(4)));
typedef float f32x2 __attribute__((ext_vector_type(2)));

__device__ __forceinline__ float fast_exp2(float x) {
    return __builtin_amdgcn_exp2f(x);
}
__device__ __forceinline__ float fast_rcp(float x) {
    return __builtin_amdgcn_rcpf(x);
}
__device__ __forceinline__ f32x2 pexp(f32x2 z) {           // scalar trans x2
    f32x2 r; r.x = fast_exp2(z.x); r.y = fast_exp2(z.y); return r;
}
__device__ __forceinline__ f32x2 prcp(f32x2 v) {           // scalar trans x2
    f32x2 r; r.x = fast_rcp(v.x); r.y = fast_rcp(v.y); return r;
}
__device__ __forceinline__ f32x2 vmin2(f32x2 v, float s) { // v_pk_min_f32
    f32x2 sv = {s, s};
    return __builtin_elementwise_min(v, sv);
}
// v ~= hi + lo (bf16 each, trunc). returns (lo<<16)|hi
__device__ __forceinline__ unsigned split_pack(float v) {
    unsigned u   = __float_as_uint(v);
    float    res = v - __uint_as_float(u & 0xffff0000u);
    return __builtin_amdgcn_perm(__float_as_uint(res), u, 0x07060302u);
}
// (a & 0xffff) | (b << 16)
__device__ __forceinline__ unsigned lo_pair(unsigned a, unsigned b) {
    return __builtin_amdgcn_perm(b, a, 0x05040100u);
}
// (a >> 16) | (b & 0xffff0000)
__device__ __forceinline__ unsigned hi_pair(unsigned a, unsigned b) {
    return __builtin_amdgcn_perm(b, a, 0x07060302u);
}
// RNE split: whi = [bf16(a) | bf16(b)], wlo = [bf16(a-hi(a)) | bf16(b-hi(b))]
__device__ __forceinline__ void pack2(float a, float b,
                                      unsigned &whi, unsigned &wlo) {
    unsigned h, l;
    asm("v_cvt_pk_bf16_f32 %0, %1, %2" : "=v"(h) : "v"(a), "v"(b));
    float ra = a - __uint_as_float(h << 16);
    float rb = b - __uint_as_float(h & 0xffff0000u);
    asm("v_cvt_pk_bf16_f32 %0, %1, %2" : "=v"(l) : "v"(ra), "v"(rb));
    whi = h; wlo = l;
}

union U4S8 { uint4 v; short8 s; unsigned u[4]; };

__global__ __launch_bounds__(256, 2)
void lsnn_kernel(const float* __restrict__ x,
                 const float* __restrict__ W_ih,
                 const float* __restrict__ W_hh,
                 const float* __restrict__ b_ih,
                 const float* __restrict__ b_hh,
                 const float* __restrict__ W_out,
                 const float* __restrict__ b_out,
                 const float* __restrict__ h0,
                 const float* __restrict__ c0,
                 float* __restrict__ out)
{
    // LDS: fused x plane 13056 B/wave + out 3200 B/wave = 65 KB/block.
    __shared__ __align__(16) unsigned xq[WPB][16 * XROW];
    __shared__ __align__(16) float    out_lds[WPB][16 * TS];

    const int  tid  = threadIdx.x;
    const int  g_w  = tid >> 6;
    const int  lane = tid & 63;
    const int  u0   = lane & 15;     // batch column (this lane's batch row)
    const int  q    = lane >> 4;     // k-block / D-row group
    const long b0   = ((long)blockIdx.x * WPB + g_w) * 16;

    unsigned* xqw = xq[g_w];
    float*    ow  = out_lds[g_w];

    // ---- stage x: fused 16B Bx frags {a0, a1, lo01, [1.0|1.0]bf16} ----
    for (int i = lane; i < 800; i += 64) {
        int row = i / 50, t = i - row * 50;          // setup-only divide
        float2 v = *(const float2*)(x + (b0 + row) * 100 + 2 * t);
        unsigned a0 = split_pack(v.x), a1 = split_pack(v.y);
        uint4 w;
        w.x = a0;                      // [xh0 | xl0]
        w.y = a1;                      // [xh1 | xl1]
        w.z = lo_pair(a0, a1);         // [xh0 | xh1]
        w.w = 0x3f803f80u;             // [1.0 | 1.0] bf16
        *(uint4*)&xqw[row * XROW + 4 * t] = w;
    }

    const float L2E = 1.4426950408889634f;
    const float SG  = 2.0f * L2E;

    // ---- stationary A-frags: tile n = ub*4 + gate; D-row m -> W_hh row
    //      R = gate*32 + ub*16 + m.  A word p = units (q*4+p, q*4+p+16). ----
    short8 Awh[8], Awl[8], Aci[8];
    #pragma unroll
    for (int n = 0; n < 8; ++n) {
        const int   g  = n & 3, ub = n >> 2;
        const float s  = (g == 2) ? SG : -L2E;
        const int   R  = g * 32 + ub * 16 + u0;
        const float* wr = W_hh + R * 32;
        U4S8 uh, ul;
        #pragma unroll
        for (int p = 0; p < 4; ++p) {
            unsigned p0 = split_pack(wr[q * 4 + p]      * s);
            unsigned p1 = split_pack(wr[q * 4 + p + 16] * s);
            uh.u[p] = lo_pair(p0, p1);
            ul.u[p] = hi_pair(p0, p1);
        }
        Awh[n] = uh.s;  Awl[n] = ul.s;
        U4S8 ux;
        if (q == 0) {   // ci k-rows 0..7: [wh0,wh0,wh1,wh1,wl0,wl1,bh,bl]
            unsigned s0 = split_pack(W_ih[R * 2 + 0] * s);
            unsigned s1 = split_pack(W_ih[R * 2 + 1] * s);
            unsigned sb = split_pack((b_ih[R] + b_hh[R]) * s);
            ux.u[0] = lo_pair(s0, s0);
            ux.u[1] = lo_pair(s1, s1);
            ux.u[2] = hi_pair(s0, s1);
            ux.u[3] = sb;
        } else {
            ux.u[0] = 0u; ux.u[1] = 0u; ux.u[2] = 0u; ux.u[3] = 0u;
        }
        Aci[n] = ux.s;
    }
    // ---- head A-frags: A[m][k] = W_out[ku(k)], uniform over m ----
    short8 Awoh, Awol;
    {
        U4S8 uh, ul;
        #pragma unroll
        for (int p = 0; p < 4; ++p) {
            unsigned p0 = split_pack(W_out[q * 4 + p]);
            unsigned p1 = split_pack(W_out[q * 4 + p + 16]);
            uh.u[p] = lo_pair(p0, p1);
            ul.u[p] = hi_pair(p0, p1);
        }
        Awoh = uh.s;  Awol = ul.s;
    }
    const float bout = b_out[0];

    // ---- h0 -> B-frags (register-resident recurrent state) ----
    U4S8 Bhh, Bhl;
    {
        const float* hp = h0 + (b0 + u0) * 32 + q * 4;
        float4 ha = *(const float4*)hp;
        float4 hb = *(const float4*)(hp + 16);
        pack2(ha.x, hb.x, Bhh.u[0], Bhl.u[0]);
        pack2(ha.y, hb.y, Bhh.u[1], Bhl.u[1]);
        pack2(ha.z, hb.z, Bhh.u[2], Bhl.u[2]);
        pack2(ha.w, hb.w, Bhh.u[3], Bhl.u[3]);
    }
    // ---- c0: group gi = ub*2+rr -> units ub*16+q*4+(2rr, 2rr+1) ----
    f32x2 cst2[4];
    #pragma unroll
    for (int ub = 0; ub < 2; ++ub)
        #pragma unroll
        for (int rr = 0; rr < 2; ++rr)
            cst2[ub * 2 + rr] =
                *(const f32x2*)(c0 + (b0 + u0) * 32 + ub * 16 + q * 4 + 2 * rr);

    const f32x4 ZV = {0.f, 0.f, 0.f, 0.f};
    const int xbase = u0 * XROW;

    // ---- x prefetch for t=0 (broadcast across q; 2-way bank alias) ----
    uint4 xw = *(const uint4*)&xqw[xbase];

    // ---- anti-phase stagger: skew one wave of each co-resident pair ----
    if (((blockIdx.x ^ (blockIdx.x >> 8)) & 1) != 0)
        __builtin_amdgcn_s_sleep(35);    // ~2240 cyc, once

    #pragma unroll 1
    for (int t = 0; t < TS; ++t) {
        U4S8 Bx;
        Bx.v = xw;
        if (t + 1 < TS)
            xw = *(const uint4*)&xqw[xbase + 4 * (t + 1)];

        // ---- output head for h_t (skip t=0): D rows all equal ----
        if (t > 0) {
            f32x4 aw = ZV;
            aw = __builtin_amdgcn_mfma_f32_16x16x32_bf16(Awoh, Bhh.s, aw, 0, 0, 0);
            aw = __builtin_amdgcn_mfma_f32_16x16x32_bf16(Awoh, Bhl.s, aw, 0, 0, 0);
            aw = __builtin_amdgcn_mfma_f32_16x16x32_bf16(Awol, Bhh.s, aw, 0, 0, 0);
            if (q == 0) ow[u0 * TS + (t - 1)] = aw[0] + bout;
        }

        // ---- gates: ci-MFMA + 3 split MFMAs per tile ----
        f32x4 acc[8];
        #pragma unroll
        for (int n = 0; n < 8; ++n)
            acc[n] = __builtin_amdgcn_mfma_f32_16x16x32_bf16(Aci[n], Bx.s, ZV, 0, 0, 0);
        #pragma unroll
        for (int n = 0; n < 8; ++n) {
            acc[n] = __builtin_amdgcn_mfma_f32_16x16x32_bf16(Awh[n], Bhh.s, acc[n], 0, 0, 0);
            acc[n] = __builtin_amdgcn_mfma_f32_16x16x32_bf16(Awh[n], Bhl.s, acc[n], 0, 0, 0);
            acc[n] = __builtin_amdgcn_mfma_f32_16x16x32_bf16(Awl[n], Bhh.s, acc[n], 0, 0, 0);
        }

        // ---- activations: 4 row-pair groups gi = ub*2+rr (fma-fused) ----
        f32x2 Bv2[4], Cv2[4], Ev2[4], P12[4], PP2[4];
        #pragma unroll
        for (int ub = 0; ub < 2; ++ub) {
            #pragma unroll
            for (int rr = 0; rr < 2; ++rr) {
                const int gi = ub * 2 + rr, nb = ub * 4;
                f32x2 zi = {acc[nb + 0][2*rr], acc[nb + 0][2*rr + 1]};
                f32x2 zf = {acc[nb + 1][2*rr], acc[nb + 1][2*rr + 1]};
                f32x2 zg = vmin2((f32x2){acc[nb + 2][2*rr], acc[nb + 2][2*rr + 1]}, CL);
                f32x2 zo = {acc[nb + 3][2*rr], acc[nb + 3][2*rr + 1]};
                f32x2 Av = pexp(zi);          // e^{-i}
                Bv2[gi]  = pexp(zg);          // e^{2g}
                Ev2[gi]  = pexp(zf);          // e^{-f}
                Cv2[gi]  = pexp(zo);          // e^{-o}
                f32x2 Ap = 1.0f + Av;
                P12[gi] = Ap * Bv2[gi] + Ap;            // (1+Av)(1+Bv)
                PP2[gi] = P12[gi] * Ev2[gi] + P12[gi];  // *(1+Ev)
            }
        }
        // ---- 4-way batched reciprocal, stage 1 (2 rcps total) ----
        f32x2 R2[4];
        {
            f32x2 s01 = PP2[0] * PP2[1];
            f32x2 s23 = PP2[2] * PP2[3];
            f32x2 ri  = prcp(s01 * s23);
            f32x2 r01 = s23 * ri;            // 1/(P0*P1)
            f32x2 r23 = s01 * ri;            // 1/(P2*P3)
            R2[0] = PP2[1] * r01;  R2[1] = PP2[0] * r01;
            R2[2] = PP2[3] * r23;  R2[3] = PP2[2] * r23;
        }
        f32x2 Dv2[4], Q2[4];
        #pragma unroll
        for (int gi = 0; gi < 4; ++gi) {
            f32x2 fv = P12[gi] * R2[gi];                 // sigmoid(f)
            f32x2 t2 = Ev2[gi] * R2[gi] + R2[gi];        // (1+Ev)*R
            f32x2 ig = Bv2[gi] * t2 - t2;                // (Bv-1)*t2
            f32x2 c  = fv * cst2[gi] + ig;
            cst2[gi] = c;
            f32x2 zc = vmin2(c * SG, CL);
            Dv2[gi] = pexp(zc);                          // e^{2c}
            f32x2 Qp = 1.0f + Cv2[gi];
            Q2[gi]  = Qp * Dv2[gi] + Qp;                 // (1+Cv)(1+Dv)
        }
        // ---- 4-way batched reciprocal, stage 2 (2 rcps total) ----
        f32x2 RQ2[4];
        {
            f32x2 s01 = Q2[0] * Q2[1];
            f32x2 s23 = Q2[2] * Q2[3];
            f32x2 ri  = prcp(s01 * s23);
            f32x2 r01 = s23 * ri;
            f32x2 r23 = s01 * ri;
            RQ2[0] = Q2[1] * r01;  RQ2[1] = Q2[0] * r01;
            RQ2[2] = Q2[3] * r23;  RQ2[3] = Q2[2] * r23;
        }
        // ---- h -> B-frag words [h(u), h(u+16)]: direct pairing ----
        f32x2 H0 = Dv2[0] * RQ2[0] - RQ2[0];
        f32x2 H1 = Dv2[1] * RQ2[1] - RQ2[1];
        f32x2 H2 = Dv2[2] * RQ2[2] - RQ2[2];
        f32x2 H3 = Dv2[3] * RQ2[3] - RQ2[3];
        pack2(H0.x, H2.x, Bhh.u[0], Bhl.u[0]);
        pack2(H0.y, H2.y, Bhh.u[1], Bhl.u[1]);
        pack2(H1.x, H3.x, Bhh.u[2], Bhl.u[2]);
        pack2(H1.y, H3.y, Bhh.u[3], Bhl.u[3]);
    }

    // ---- final head for h_50 ----
    {
        f32x4 aw = {0.f, 0.f, 0.f, 0.f};
        aw = __builtin_amdgcn_mfma_f32_16x16x32_bf16(Awoh, Bhh.s, aw, 0, 0, 0);
        aw = __builtin_amdgcn_mfma_f32_16x16x32_bf16(Awoh, Bhl.s, aw, 0, 0, 0);
        aw = __builtin_amdgcn_mfma_f32_16x16x32_bf16(Awol, Bhh.s, aw, 0, 0, 0);
        if (q == 0) ow[u0 * TS + 49] = aw[0] + bout;
    }

    // ---- coalesced flush of this wave's 800 contiguous floats ----
    {
        float4* od = (float4*)(out + b0 * 50);
        const float4* os = (const float4*)ow;
        for (int i = lane; i < 200; i += 64) od[i] = os[i];
    }
}

extern "C" void kernel_launch(void* const* d_in, const int* in_sizes, int n_in,
                              void* d_out, int out_size, void* d_ws, size_t ws_size,
                              hipStream_t stream) {
    const float* x     = (const float*)d_in[0];
    const float* W_ih  = (const float*)d_in[1];
    const float* W_hh  = (const float*)d_in[2];
    const float* b_ih  = (const float*)d_in[3];
    const float* b_hh  = (const float*)d_in[4];
    const float* W_out = (const float*)d_in[5];
    const float* b_out = (const float*)d_in[6];
    const float* h0    = (const float*)d_in[7];
    const float* c0    = (const float*)d_in[8];
    float* out = (float*)d_out;

    dim3 grid(32768 / (16 * WPB)), block(64 * WPB);
    lsnn_kernel<<<grid, block, 0, stream>>>(x, W_ih, W_hh, b_ih, b_hh,
                                            W_out, b_out, h0, c0, out);
}

// Round 11
// 135.624 us; speedup vs baseline: 1.1644x; 1.0945x over previous
//
#include <hip/hip_runtime.h>

// LSTM B=32768, T=50, I=2, H=32.
// R23 = R22 resubmit (infra failure, kernel never ran). f16 SINGLE-PASS
// MFMA replaces bf16 split-precision. Rationale: f16 MFMA rate == bf16
// rate (1955 vs 2075 TF ubench) but 11-bit mantissa -> single-pass
// z-error ~sqrt(32)*|W||h|*2^-11 ~ 2-3e-4 rms, inside tolerance. Cuts the
// largest untouched counted block: gate MFMAs 24->8, head 3->1, total
// 35->17/wave-t (-90 weighted cyc); h-repack 4xpack2(16 ops) -> 4x
// v_cvt_pkrtz (-24 cyc); Bx = one ds_read_b32 + const word. ~-115 of
// ~1210 cyc -> predict ~79-83us.
// Model (fitted R12-R20): SIMD port serializes pipes; wall tracks
// sum(2*VALU + 16*trans + ~5*MFMA). Trans floor 704 cyc (40 exp + 4
// batched rcp) irreducible (R16: VALU-poly loses; R19: rcp batched).
// Parallelism null at all granularities (R14/R18).
// Carried: transposed GEMM (A=W stationary, B=h register-resident, word p
// of any frag = units (q*4+p, q*4+p+16) -- only A/B word-position
// consistency matters), MFMA ci-init (x-proj+bias), row-pair pk
// activations, fma-fused algebra, 4-way batched rcp, scales folded
// (-log2e/+2log2e), pk-min clamps on zg and c (CL=14), anti-phase stagger.

#define TS 50
#define XSTR 51     // u32 stride of x plane rows (odd: conflict-free bcast)
#define CL 14.0f
#define WPB 4       // waves per block (independent; no barriers)

typedef _Float16 half8 __attribute__((ext_vector_type(8)));
typedef float f32x4 __attribute__((ext_vector_type(4)));
typedef float f32x2 __attribute__((ext_vector_type(2)));

__device__ __forceinline__ float fast_exp2(float x) {
    return __builtin_amdgcn_exp2f(x);
}
__device__ __forceinline__ float fast_rcp(float x) {
    return __builtin_amdgcn_rcpf(x);
}
__device__ __forceinline__ f32x2 pexp(f32x2 z) {           // scalar trans x2
    f32x2 r; r.x = fast_exp2(z.x); r.y = fast_exp2(z.y); return r;
}
__device__ __forceinline__ f32x2 prcp(f32x2 v) {           // scalar trans x2
    f32x2 r; r.x = fast_rcp(v.x); r.y = fast_rcp(v.y); return r;
}
__device__ __forceinline__ f32x2 vmin2(f32x2 v, float s) { // v_pk_min_f32
    f32x2 sv = {s, s};
    return __builtin_elementwise_min(v, sv);
}
// packed f32x2 -> f16x2 word (RTZ), single v_cvt_pkrtz_f16_f32
__device__ __forceinline__ unsigned pkrtz(float a, float b) {
    auto h = __builtin_amdgcn_cvt_pkrtz(a, b);   // __fp16 ext_vector(2)
    return __builtin_bit_cast(unsigned, h);
}

union U4H8 { uint4 v; half8 h; unsigned u[4]; };

__global__ __launch_bounds__(256, 2)
void lsnn_kernel(const float* __restrict__ x,
                 const float* __restrict__ W_ih,
                 const float* __restrict__ W_hh,
                 const float* __restrict__ b_ih,
                 const float* __restrict__ b_hh,
                 const float* __restrict__ W_out,
                 const float* __restrict__ b_out,
                 const float* __restrict__ h0,
                 const float* __restrict__ c0,
                 float* __restrict__ out)
{
    // LDS: x plane 3264 B/wave + out 3200 B/wave = 25.9 KB/block.
    __shared__ __align__(16) unsigned xq[WPB][16 * XSTR];
    __shared__ __align__(16) float    out_lds[WPB][16 * TS];

    const int  tid  = threadIdx.x;
    const int  g_w  = tid >> 6;
    const int  lane = tid & 63;
    const int  u0   = lane & 15;     // batch column (this lane's batch row)
    const int  q    = lane >> 4;     // k-block / D-row group
    const long b0   = ((long)blockIdx.x * WPB + g_w) * 16;

    unsigned* xqw = xq[g_w];
    float*    ow  = out_lds[g_w];

    // ---- stage x: one f16x2 word {x0, x1} per (row, t) ----
    for (int i = lane; i < 800; i += 64) {
        int row = i / 50, t = i - row * 50;          // setup-only divide
        float2 v = *(const float2*)(x + (b0 + row) * 100 + 2 * t);
        xqw[row * XSTR + t] = pkrtz(v.x, v.y);
    }

    const float L2E = 1.4426950408889634f;
    const float SG  = 2.0f * L2E;

    // ---- stationary A-frags (f16): tile n = ub*4 + gate; D-row m ->
    //      W_hh row R = gate*32 + ub*16 + m.
    //      A word p = units (q*4+p, q*4+p+16). ----
    U4H8 Aw[8], Aci[8];
    #pragma unroll
    for (int n = 0; n < 8; ++n) {
        const int   g  = n & 3, ub = n >> 2;
        const float s  = (g == 2) ? SG : -L2E;
        const int   R  = g * 32 + ub * 16 + u0;
        const float* wr = W_hh + R * 32;
        #pragma unroll
        for (int p = 0; p < 4; ++p)
            Aw[n].u[p] = pkrtz(wr[q * 4 + p] * s, wr[q * 4 + p + 16] * s);
        if (q == 0) {   // ci k-rows: word0 = (w0,w1), word1 = (bias, 0)
            Aci[n].u[0] = pkrtz(W_ih[R * 2 + 0] * s, W_ih[R * 2 + 1] * s);
            Aci[n].u[1] = pkrtz((b_ih[R] + b_hh[R]) * s, 0.0f);
            Aci[n].u[2] = 0u;  Aci[n].u[3] = 0u;
        } else {
            Aci[n].u[0] = 0u; Aci[n].u[1] = 0u; Aci[n].u[2] = 0u; Aci[n].u[3] = 0u;
        }
    }
    // ---- head A-frag: A[m][k] = W_out[unit(k)], uniform over m ----
    U4H8 Awo;
    #pragma unroll
    for (int p = 0; p < 4; ++p)
        Awo.u[p] = pkrtz(W_out[q * 4 + p], W_out[q * 4 + p + 16]);
    const float bout = b_out[0];

    // ---- h0 -> B-frag (register-resident recurrent state, f16) ----
    U4H8 Bh;
    {
        const float* hp = h0 + (b0 + u0) * 32 + q * 4;
        float4 ha = *(const float4*)hp;
        float4 hb = *(const float4*)(hp + 16);
        Bh.u[0] = pkrtz(ha.x, hb.x);
        Bh.u[1] = pkrtz(ha.y, hb.y);
        Bh.u[2] = pkrtz(ha.z, hb.z);
        Bh.u[3] = pkrtz(ha.w, hb.w);
    }
    // ---- c0: group gi = ub*2+rr -> units ub*16+q*4+(2rr, 2rr+1) ----
    f32x2 cst2[4];
    #pragma unroll
    for (int ub = 0; ub < 2; ++ub)
        #pragma unroll
        for (int rr = 0; rr < 2; ++rr)
            cst2[ub * 2 + rr] =
                *(const f32x2*)(c0 + (b0 + u0) * 32 + ub * 16 + q * 4 + 2 * rr);

    const f32x4 ZV = {0.f, 0.f, 0.f, 0.f};
    const int xbase = u0 * XSTR;

    // ---- x prefetch for t=0 (broadcast across q) ----
    unsigned xw = xqw[xbase];

    // ---- anti-phase stagger: skew one wave of each co-resident pair ----
    if (((blockIdx.x ^ (blockIdx.x >> 8)) & 1) != 0)
        __builtin_amdgcn_s_sleep(35);    // ~2240 cyc, once

    #pragma unroll 1
    for (int t = 0; t < TS; ++t) {
        U4H8 Bx;
        Bx.u[0] = xw;                    // (x0, x1) f16 pair
        Bx.u[1] = 0x00003c00u;           // (1.0, 0.0) f16
        Bx.u[2] = 0u;  Bx.u[3] = 0u;
        if (t + 1 < TS)
            xw = xqw[xbase + t + 1];

        // ---- output head for h_t (skip t=0): D rows all equal ----
        if (t > 0) {
            f32x4 aw = __builtin_amdgcn_mfma_f32_16x16x32_f16(Awo.h, Bh.h, ZV, 0, 0, 0);
            if (q == 0) ow[u0 * TS + (t - 1)] = aw[0] + bout;
        }

        // ---- gates: ci-MFMA + 1 f16 MFMA per tile ----
        f32x4 acc[8];
        #pragma unroll
        for (int n = 0; n < 8; ++n)
            acc[n] = __builtin_amdgcn_mfma_f32_16x16x32_f16(Aci[n].h, Bx.h, ZV, 0, 0, 0);
        #pragma unroll
        for (int n = 0; n < 8; ++n)
            acc[n] = __builtin_amdgcn_mfma_f32_16x16x32_f16(Aw[n].h, Bh.h, acc[n], 0, 0, 0);

        // ---- activations: 4 row-pair groups gi = ub*2+rr (fma-fused) ----
        f32x2 Bv2[4], Cv2[4], Ev2[4], P12[4], PP2[4];
        #pragma unroll
        for (int ub = 0; ub < 2; ++ub) {
            #pragma unroll
            for (int rr = 0; rr < 2; ++rr) {
                const int gi = ub * 2 + rr, nb = ub * 4;
                f32x2 zi = {acc[nb + 0][2*rr], acc[nb + 0][2*rr + 1]};
                f32x2 zf = {acc[nb + 1][2*rr], acc[nb + 1][2*rr + 1]};
                f32x2 zg = vmin2((f32x2){acc[nb + 2][2*rr], acc[nb + 2][2*rr + 1]}, CL);
                f32x2 zo = {acc[nb + 3][2*rr], acc[nb + 3][2*rr + 1]};
                f32x2 Av = pexp(zi);          // e^{-i}
                Bv2[gi]  = pexp(zg);          // e^{2g}
                Ev2[gi]  = pexp(zf);          // e^{-f}
                Cv2[gi]  = pexp(zo);          // e^{-o}
                f32x2 Ap = 1.0f + Av;
                P12[gi] = Ap * Bv2[gi] + Ap;            // (1+Av)(1+Bv)
                PP2[gi] = P12[gi] * Ev2[gi] + P12[gi];  // *(1+Ev)
            }
        }
        // ---- 4-way batched reciprocal, stage 1 (2 rcps total) ----
        f32x2 R2[4];
        {
            f32x2 s01 = PP2[0] * PP2[1];
            f32x2 s23 = PP2[2] * PP2[3];
            f32x2 ri  = prcp(s01 * s23);
            f32x2 r01 = s23 * ri;            // 1/(P0*P1)
            f32x2 r23 = s01 * ri;            // 1/(P2*P3)
            R2[0] = PP2[1] * r01;  R2[1] = PP2[0] * r01;
            R2[2] = PP2[3] * r23;  R2[3] = PP2[2] * r23;
        }
        f32x2 Dv2[4], Q2[4];
        #pragma unroll
        for (int gi = 0; gi < 4; ++gi) {
            f32x2 fv = P12[gi] * R2[gi];                 // sigmoid(f)
            f32x2 t2 = Ev2[gi] * R2[gi] + R2[gi];        // (1+Ev)*R
            f32x2 ig = Bv2[gi] * t2 - t2;                // (Bv-1)*t2
            f32x2 c  = fv * cst2[gi] + ig;
            cst2[gi] = c;
            f32x2 zc = vmin2(c * SG, CL);
            Dv2[gi] = pexp(zc);                          // e^{2c}
            f32x2 Qp = 1.0f + Cv2[gi];
            Q2[gi]  = Qp * Dv2[gi] + Qp;                 // (1+Cv)(1+Dv)
        }
        // ---- 4-way batched reciprocal, stage 2 (2 rcps total) ----
        f32x2 RQ2[4];
        {
            f32x2 s01 = Q2[0] * Q2[1];
            f32x2 s23 = Q2[2] * Q2[3];
            f32x2 ri  = prcp(s01 * s23);
            f32x2 r01 = s23 * ri;
            f32x2 r23 = s01 * ri;
            RQ2[0] = Q2[1] * r01;  RQ2[1] = Q2[0] * r01;
            RQ2[2] = Q2[3] * r23;  RQ2[3] = Q2[2] * r23;
        }
        // ---- h -> B-frag words [h(u), h(u+16)]: 4x cvt_pkrtz ----
        f32x2 H0 = Dv2[0] * RQ2[0] - RQ2[0];
        f32x2 H1 = Dv2[1] * RQ2[1] - RQ2[1];
        f32x2 H2 = Dv2[2] * RQ2[2] - RQ2[2];
        f32x2 H3 = Dv2[3] * RQ2[3] - RQ2[3];
        Bh.u[0] = pkrtz(H0.x, H2.x);
        Bh.u[1] = pkrtz(H0.y, H2.y);
        Bh.u[2] = pkrtz(H1.x, H3.x);
        Bh.u[3] = pkrtz(H1.y, H3.y);
    }

    // ---- final head for h_50 ----
    {
        f32x4 aw = __builtin_amdgcn_mfma_f32_16x16x32_f16(Awo.h, Bh.h, ZV, 0, 0, 0);
        if (q == 0) ow[u0 * TS + 49] = aw[0] + bout;
    }

    // ---- coalesced flush of this wave's 800 contiguous floats ----
    {
        float4* od = (float4*)(out + b0 * 50);
        const float4* os = (const float4*)ow;
        for (int i = lane; i < 200; i += 64) od[i] = os[i];
    }
}

extern "C" void kernel_launch(void* const* d_in, const int* in_sizes, int n_in,
                              void* d_out, int out_size, void* d_ws, size_t ws_size,
                              hipStream_t stream) {
    const float* x     = (const float*)d_in[0];
    const float* W_ih  = (const float*)d_in[1];
    const float* W_hh  = (const float*)d_in[2];
    const float* b_ih  = (const float*)d_in[3];
    const float* b_hh  = (const float*)d_in[4];
    const float* W_out = (const float*)d_in[5];
    const float* b_out = (const float*)d_in[6];
    const float* h0    = (const float*)d_in[7];
    const float* c0    = (const float*)d_in[8];
    float* out = (float*)d_out;

    dim3 grid(32768 / (16 * WPB)), block(64 * WPB);
    lsnn_kernel<<<grid, block, 0, stream>>>(x, W_ih, W_hh, b_ih, b_hh,
                                            W_out, b_out, h0, c0, out);
}

// Round 12
// 131.656 us; speedup vs baseline: 1.1995x; 1.0301x over previous
//
#include <hip/hip_runtime.h>

// LSTM B=32768, T=50, I=2, H=32.
// R24 = R23 (69.4-70.6us) + final counted shaves. R23 post-mortem: f16
// single-pass cut wall 21%; counted issue (~960 cyc/wave-t = 704 trans +
// ~170 VALU + ~85 MFMA) now ~= wall (980) -> SIMD issue port ~98%
// occupied, trans 73% and irreducible (5 exp/element LSTM minimum; R16:
// VALU-poly loses; R19: rcp 4-way batched, 8-way overflows f32).
// This round: (1) +bout folded into flush epilogue (kills per-t dependent
// add on head path, ~4 cyc/wave-t); (2) gate MFMAs issued BEFORE head
// MFMA (head is chain tail -> store; gates feed the exp burst: activation
// chain starts earlier); (3) Bx constant words hoisted (persistent reg).
// If null (>=69.5us): counted floor reached -> declare roofline.
// Carried: transposed GEMM (A=W stationary, B=h register-resident, word p
// of any frag = units (q*4+p, q*4+p+16)), f16 single-pass MFMA (gate 8 +
// ci 8 + head 1), MFMA ci-init, row-pair pk activations, fma-fused
// algebra, 4-way batched rcp, scales folded (-log2e/+2log2e), pk-min
// clamps on zg and c (CL=14, protects batched-rcp overflow), anti-phase
// stagger, x pre-packed f16 LDS plane.

#define TS 50
#define XSTR 51     // u32 stride of x plane rows (odd: conflict-free bcast)
#define CL 14.0f
#define WPB 4       // waves per block (independent; no barriers)

typedef _Float16 half8 __attribute__((ext_vector_type(8)));
typedef float f32x4 __attribute__((ext_vector_type(4)));
typedef float f32x2 __attribute__((ext_vector_type(2)));

__device__ __forceinline__ float fast_exp2(float x) {
    return __builtin_amdgcn_exp2f(x);
}
__device__ __forceinline__ float fast_rcp(float x) {
    return __builtin_amdgcn_rcpf(x);
}
__device__ __forceinline__ f32x2 pexp(f32x2 z) {           // scalar trans x2
    f32x2 r; r.x = fast_exp2(z.x); r.y = fast_exp2(z.y); return r;
}
__device__ __forceinline__ f32x2 prcp(f32x2 v) {           // scalar trans x2
    f32x2 r; r.x = fast_rcp(v.x); r.y = fast_rcp(v.y); return r;
}
__device__ __forceinline__ f32x2 vmin2(f32x2 v, float s) { // v_pk_min_f32
    f32x2 sv = {s, s};
    return __builtin_elementwise_min(v, sv);
}
// packed f32x2 -> f16x2 word (RTZ), single v_cvt_pkrtz_f16_f32
__device__ __forceinline__ unsigned pkrtz(float a, float b) {
    auto h = __builtin_amdgcn_cvt_pkrtz(a, b);   // __fp16 ext_vector(2)
    return __builtin_bit_cast(unsigned, h);
}

union U4H8 { uint4 v; half8 h; unsigned u[4]; };

__global__ __launch_bounds__(256, 2)
void lsnn_kernel(const float* __restrict__ x,
                 const float* __restrict__ W_ih,
                 const float* __restrict__ W_hh,
                 const float* __restrict__ b_ih,
                 const float* __restrict__ b_hh,
                 const float* __restrict__ W_out,
                 const float* __restrict__ b_out,
                 const float* __restrict__ h0,
                 const float* __restrict__ c0,
                 float* __restrict__ out)
{
    // LDS: x plane 3264 B/wave + out 3200 B/wave = 25.9 KB/block.
    __shared__ __align__(16) unsigned xq[WPB][16 * XSTR];
    __shared__ __align__(16) float    out_lds[WPB][16 * TS];

    const int  tid  = threadIdx.x;
    const int  g_w  = tid >> 6;
    const int  lane = tid & 63;
    const int  u0   = lane & 15;     // batch column (this lane's batch row)
    const int  q    = lane >> 4;     // k-block / D-row group
    const long b0   = ((long)blockIdx.x * WPB + g_w) * 16;

    unsigned* xqw = xq[g_w];
    float*    ow  = out_lds[g_w];

    // ---- stage x: one f16x2 word {x0, x1} per (row, t) ----
    for (int i = lane; i < 800; i += 64) {
        int row = i / 50, t = i - row * 50;          // setup-only divide
        float2 v = *(const float2*)(x + (b0 + row) * 100 + 2 * t);
        xqw[row * XSTR + t] = pkrtz(v.x, v.y);
    }

    const float L2E = 1.4426950408889634f;
    const float SG  = 2.0f * L2E;

    // ---- stationary A-frags (f16): tile n = ub*4 + gate; D-row m ->
    //      W_hh row R = gate*32 + ub*16 + m.
    //      A word p = units (q*4+p, q*4+p+16). ----
    U4H8 Aw[8], Aci[8];
    #pragma unroll
    for (int n = 0; n < 8; ++n) {
        const int   g  = n & 3, ub = n >> 2;
        const float s  = (g == 2) ? SG : -L2E;
        const int   R  = g * 32 + ub * 16 + u0;
        const float* wr = W_hh + R * 32;
        #pragma unroll
        for (int p = 0; p < 4; ++p)
            Aw[n].u[p] = pkrtz(wr[q * 4 + p] * s, wr[q * 4 + p + 16] * s);
        if (q == 0) {   // ci k-rows: word0 = (w0,w1), word1 = (bias, 0)
            Aci[n].u[0] = pkrtz(W_ih[R * 2 + 0] * s, W_ih[R * 2 + 1] * s);
            Aci[n].u[1] = pkrtz((b_ih[R] + b_hh[R]) * s, 0.0f);
            Aci[n].u[2] = 0u;  Aci[n].u[3] = 0u;
        } else {
            Aci[n].u[0] = 0u; Aci[n].u[1] = 0u; Aci[n].u[2] = 0u; Aci[n].u[3] = 0u;
        }
    }
    // ---- head A-frag: A[m][k] = W_out[unit(k)], uniform over m ----
    U4H8 Awo;
    #pragma unroll
    for (int p = 0; p < 4; ++p)
        Awo.u[p] = pkrtz(W_out[q * 4 + p], W_out[q * 4 + p + 16]);
    const float bout = b_out[0];

    // ---- h0 -> B-frag (register-resident recurrent state, f16) ----
    U4H8 Bh;
    {
        const float* hp = h0 + (b0 + u0) * 32 + q * 4;
        float4 ha = *(const float4*)hp;
        float4 hb = *(const float4*)(hp + 16);
        Bh.u[0] = pkrtz(ha.x, hb.x);
        Bh.u[1] = pkrtz(ha.y, hb.y);
        Bh.u[2] = pkrtz(ha.z, hb.z);
        Bh.u[3] = pkrtz(ha.w, hb.w);
    }
    // ---- c0: group gi = ub*2+rr -> units ub*16+q*4+(2rr, 2rr+1) ----
    f32x2 cst2[4];
    #pragma unroll
    for (int ub = 0; ub < 2; ++ub)
        #pragma unroll
        for (int rr = 0; rr < 2; ++rr)
            cst2[ub * 2 + rr] =
                *(const f32x2*)(c0 + (b0 + u0) * 32 + ub * 16 + q * 4 + 2 * rr);

    const f32x4 ZV = {0.f, 0.f, 0.f, 0.f};
    const int xbase = u0 * XSTR;

    // ---- Bx: constant words persistent; word0 refreshed per t ----
    U4H8 Bx;
    Bx.u[0] = xqw[xbase];            // t=0 prefetch
    Bx.u[1] = 0x00003c00u;           // (1.0, 0.0) f16
    Bx.u[2] = 0u;  Bx.u[3] = 0u;

    // ---- anti-phase stagger: skew one wave of each co-resident pair ----
    if (((blockIdx.x ^ (blockIdx.x >> 8)) & 1) != 0)
        __builtin_amdgcn_s_sleep(35);    // ~2240 cyc, once

    #pragma unroll 1
    for (int t = 0; t < TS; ++t) {
        // ---- gates FIRST (feed the exp burst): ci-MFMA + 1 MFMA/tile ----
        f32x4 acc[8];
        #pragma unroll
        for (int n = 0; n < 8; ++n)
            acc[n] = __builtin_amdgcn_mfma_f32_16x16x32_f16(Aci[n].h, Bx.h, ZV, 0, 0, 0);
        #pragma unroll
        for (int n = 0; n < 8; ++n)
            acc[n] = __builtin_amdgcn_mfma_f32_16x16x32_f16(Aw[n].h, Bh.h, acc[n], 0, 0, 0);

        // ---- head for h_t (chain tail; skip t=0); raw store, +bout in
        //      flush epilogue ----
        if (t > 0) {
            f32x4 aw = __builtin_amdgcn_mfma_f32_16x16x32_f16(Awo.h, Bh.h, ZV, 0, 0, 0);
            if (q == 0) ow[u0 * TS + (t - 1)] = aw[0];
        }

        // ---- x word for t+1 ----
        if (t + 1 < TS)
            Bx.u[0] = xqw[xbase + t + 1];

        // ---- activations: 4 row-pair groups gi = ub*2+rr (fma-fused) ----
        f32x2 Bv2[4], Cv2[4], Ev2[4], P12[4], PP2[4];
        #pragma unroll
        for (int ub = 0; ub < 2; ++ub) {
            #pragma unroll
            for (int rr = 0; rr < 2; ++rr) {
                const int gi = ub * 2 + rr, nb = ub * 4;
                f32x2 zi = {acc[nb + 0][2*rr], acc[nb + 0][2*rr + 1]};
                f32x2 zf = {acc[nb + 1][2*rr], acc[nb + 1][2*rr + 1]};
                f32x2 zg = vmin2((f32x2){acc[nb + 2][2*rr], acc[nb + 2][2*rr + 1]}, CL);
                f32x2 zo = {acc[nb + 3][2*rr], acc[nb + 3][2*rr + 1]};
                f32x2 Av = pexp(zi);          // e^{-i}
                Bv2[gi]  = pexp(zg);          // e^{2g}
                Ev2[gi]  = pexp(zf);          // e^{-f}
                Cv2[gi]  = pexp(zo);          // e^{-o}
                f32x2 Ap = 1.0f + Av;
                P12[gi] = Ap * Bv2[gi] + Ap;            // (1+Av)(1+Bv)
                PP2[gi] = P12[gi] * Ev2[gi] + P12[gi];  // *(1+Ev)
            }
        }
        // ---- 4-way batched reciprocal, stage 1 (2 rcps total) ----
        f32x2 R2[4];
        {
            f32x2 s01 = PP2[0] * PP2[1];
            f32x2 s23 = PP2[2] * PP2[3];
            f32x2 ri  = prcp(s01 * s23);
            f32x2 r01 = s23 * ri;            // 1/(P0*P1)
            f32x2 r23 = s01 * ri;            // 1/(P2*P3)
            R2[0] = PP2[1] * r01;  R2[1] = PP2[0] * r01;
            R2[2] = PP2[3] * r23;  R2[3] = PP2[2] * r23;
        }
        f32x2 Dv2[4], Q2[4];
        #pragma unroll
        for (int gi = 0; gi < 4; ++gi) {
            f32x2 fv = P12[gi] * R2[gi];                 // sigmoid(f)
            f32x2 t2 = Ev2[gi] * R2[gi] + R2[gi];        // (1+Ev)*R
            f32x2 ig = Bv2[gi] * t2 - t2;                // (Bv-1)*t2
            f32x2 c  = fv * cst2[gi] + ig;
            cst2[gi] = c;
            f32x2 zc = vmin2(c * SG, CL);
            Dv2[gi] = pexp(zc);                          // e^{2c}
            f32x2 Qp = 1.0f + Cv2[gi];
            Q2[gi]  = Qp * Dv2[gi] + Qp;                 // (1+Cv)(1+Dv)
        }
        // ---- 4-way batched reciprocal, stage 2 (2 rcps total) ----
        f32x2 RQ2[4];
        {
            f32x2 s01 = Q2[0] * Q2[1];
            f32x2 s23 = Q2[2] * Q2[3];
            f32x2 ri  = prcp(s01 * s23);
            f32x2 r01 = s23 * ri;
            f32x2 r23 = s01 * ri;
            RQ2[0] = Q2[1] * r01;  RQ2[1] = Q2[0] * r01;
            RQ2[2] = Q2[3] * r23;  RQ2[3] = Q2[2] * r23;
        }
        // ---- h -> B-frag words [h(u), h(u+16)]: 4x cvt_pkrtz ----
        f32x2 H0 = Dv2[0] * RQ2[0] - RQ2[0];
        f32x2 H1 = Dv2[1] * RQ2[1] - RQ2[1];
        f32x2 H2 = Dv2[2] * RQ2[2] - RQ2[2];
        f32x2 H3 = Dv2[3] * RQ2[3] - RQ2[3];
        Bh.u[0] = pkrtz(H0.x, H2.x);
        Bh.u[1] = pkrtz(H0.y, H2.y);
        Bh.u[2] = pkrtz(H1.x, H3.x);
        Bh.u[3] = pkrtz(H1.y, H3.y);
    }

    // ---- final head for h_50 ----
    {
        f32x4 aw = __builtin_amdgcn_mfma_f32_16x16x32_f16(Awo.h, Bh.h, ZV, 0, 0, 0);
        if (q == 0) ow[u0 * TS + 49] = aw[0];
    }

    // ---- coalesced flush of this wave's 800 floats, +bout applied ----
    {
        float4* od = (float4*)(out + b0 * 50);
        const float4* os = (const float4*)ow;
        for (int i = lane; i < 200; i += 64) {
            float4 v = os[i];
            v.x += bout; v.y += bout; v.z += bout; v.w += bout;
            od[i] = v;
        }
    }
}

extern "C" void kernel_launch(void* const* d_in, const int* in_sizes, int n_in,
                              void* d_out, int out_size, void* d_ws, size_t ws_size,
                              hipStream_t stream) {
    const float* x     = (const float*)d_in[0];
    const float* W_ih  = (const float*)d_in[1];
    const float* W_hh  = (const float*)d_in[2];
    const float* b_ih  = (const float*)d_in[3];
    const float* b_hh  = (const float*)d_in[4];
    const float* W_out = (const float*)d_in[5];
    const float* b_out = (const float*)d_in[6];
    const float* h0    = (const float*)d_in[7];
    const float* c0    = (const float*)d_in[8];
    float* out = (float*)d_out;

    dim3 grid(32768 / (16 * WPB)), block(64 * WPB);
    lsnn_kernel<<<grid, block, 0, stream>>>(x, W_ih, W_hh, b_ih, b_hh,
                                            W_out, b_out, h0, c0, out);
}